// Round 13
// baseline (206.347 us; speedup 1.0000x reference)
//
#include <hip/hip_runtime.h>

typedef __bf16 bf16x8 __attribute__((ext_vector_type(8)));
typedef float f32x4 __attribute__((ext_vector_type(4)));
typedef unsigned short ushort8v __attribute__((ext_vector_type(8)));

#define NB 16
#define NT 4096
#define NV 32000
#define ND 512
#define NH 1024
#define NSLOTS 256

__device__ __forceinline__ float b2f(unsigned short u) {
  unsigned int x = ((unsigned int)u) << 16;
  return __builtin_bit_cast(float, x);
}
__device__ __forceinline__ unsigned short f2b(float f) {
  unsigned int x = __builtin_bit_cast(unsigned int, f);
  unsigned int r = (x + 0x7FFFu + ((x >> 16) & 1u)) >> 16;
  return (unsigned short)r;
}

#define GLOAD_LDS16(g, l)                                                              \
  __builtin_amdgcn_global_load_lds((const __attribute__((address_space(1))) void*)(g), \
                                   (__attribute__((address_space(3))) void*)(l), 16, 0, 0)
#define BARRIER() asm volatile("s_barrier" ::: "memory")
#define VMCNT(n) asm volatile("s_waitcnt vmcnt(" #n ")" ::: "memory")

// ---------------------------------------------------------------------------
// Fused elementwise prep: emb f32->bf16 (blocks <8000) and w1/w2 transpose+cvt.
// ---------------------------------------------------------------------------
__global__ __launch_bounds__(256) void cvtwt_kernel(
    const float* __restrict__ emb, unsigned short* __restrict__ embb,
    const float* __restrict__ w1, const float* __restrict__ w2,
    unsigned short* __restrict__ w1t, unsigned short* __restrict__ w2t) {
  const int blk = blockIdx.x;
  if (blk < 8000) {
    const long base = ((long)blk * 256 + threadIdx.x) * 8;
    float4 a = *(const float4*)&emb[base];
    float4 b = *(const float4*)&emb[base + 4];
    ushort8v o;
    o[0] = f2b(a.x); o[1] = f2b(a.y); o[2] = f2b(a.z); o[3] = f2b(a.w);
    o[4] = f2b(b.x); o[5] = f2b(b.y); o[6] = f2b(b.z); o[7] = f2b(b.w);
    *(ushort8v*)&embb[base] = o;
  } else {
    const int i = (blk - 8000) * 256 + threadIdx.x;
    if (i < ND * NH) {
      const int n = i >> 9, k = i & 511;
      w1t[i] = f2b(w1[k * NH + n]);
    } else {
      const int j = i - ND * NH;
      const int n = j >> 10, k = j & 1023;
      w2t[j] = f2b(w2[k * ND + n]);
    }
  }
}

// ---------------------------------------------------------------------------
// 128x128 bf16 MFMA GEMM over VOCAB rows (M = 32000 = 250 tiles) — the r6
// structure that measured 683 TF: BK=32, 3-deep buffer pipeline with counted
// vmcnt (loads in flight across raw s_barriers), XOR-swizzled LDS (linear
// gload_lds dest + pre-swizzled global src + swizzled ds_read), XCD block
// swizzle (grid % 8 == 0), setprio around MFMA cluster. 4 waves (2x2),
// 48 KiB LDS -> 3 blocks/CU inter-block pipe overlap.
// ---------------------------------------------------------------------------
template <int KDIM, int NLD, int NBN, bool RELU>
__global__ __launch_bounds__(256) void gemm128_kernel(
    const unsigned short* __restrict__ Abase, const unsigned short* __restrict__ Bt,
    const float* __restrict__ bias, unsigned short* __restrict__ Out) {
  __shared__ union {
    unsigned short AB[3][2][128 * 32];  // [buf][A/B][row*32 + chunk*8]
    unsigned short C[128 * 136];        // padded epilogue tile
  } sm;
  const int tid = threadIdx.x;
  const int lane = tid & 63;
  const int w = tid >> 6;

  // XCD-aware bijective swizzle (gridDim.x % 8 == 0)
  const int id = blockIdx.x;
  const int swz = (id & 7) * (gridDim.x >> 3) + (id >> 3);
  const int bm = swz / NBN;
  const int bn = swz % NBN;

  const int wm = w >> 1, wn = w & 1;

  // Staging: wave w stages row-groups {2w,2w+1} of A and B.
  // LDS slot (row, c) holds global chunk c ^ ((row>>1)&3)  (pre-swizzled src).
  const int rgrp = lane >> 2;
  const int schunk = (lane & 3) ^ ((lane >> 3) & 3);
  const unsigned short* aptr[2];
  const unsigned short* bptr[2];
#pragma unroll
  for (int r = 0; r < 2; ++r) {
    const int grp = w * 2 + r;
    const int arow = bm * 128 + grp * 16 + rgrp;
    aptr[r] = Abase + (size_t)arow * (size_t)KDIM + schunk * 8;
    const int brow = bn * 128 + grp * 16 + rgrp;
    bptr[r] = Bt + (size_t)brow * (size_t)KDIM + schunk * 8;
  }

  // Fragment read offsets (shorts), same swizzle on the read side.
  const int fr = lane & 15;
  const int fhi = lane >> 4;
  const int fsw = (fr >> 1) & 3;
  const int fchunk = (fhi ^ fsw) * 8;
  int aoff[4], boff[4];
#pragma unroll
  for (int m = 0; m < 4; ++m) aoff[m] = (wm * 64 + m * 16 + fr) * 32 + fchunk;
#pragma unroll
  for (int n = 0; n < 4; ++n) boff[n] = (wn * 64 + n * 16 + fr) * 32 + fchunk;

  f32x4 acc[4][4] = {};

  auto stage = [&](int buf, int kt) {
#pragma unroll
    for (int r = 0; r < 2; ++r) {
      const int grp = w * 2 + r;
      GLOAD_LDS16(aptr[r] + kt * 32, &sm.AB[buf][0][grp * 512]);
      GLOAD_LDS16(bptr[r] + kt * 32, &sm.AB[buf][1][grp * 512]);
    }
  };

  constexpr int NKT = KDIM / 32;
  stage(0, 0);
  stage(1, 1);
  for (int kt = 0; kt < NKT; ++kt) {
    if (kt + 1 < NKT)
      asm volatile("s_waitcnt vmcnt(4)" ::: "memory");
    else
      asm volatile("s_waitcnt vmcnt(0)" ::: "memory");
    __builtin_amdgcn_s_barrier();
    if (kt + 2 < NKT) stage((kt + 2) % 3, kt + 2);
    const int cur = kt % 3;
    bf16x8 af[4], bfr[4];
#pragma unroll
    for (int m = 0; m < 4; ++m)
      af[m] = __builtin_bit_cast(bf16x8, *(const ushort8v*)&sm.AB[cur][0][aoff[m]]);
#pragma unroll
    for (int n = 0; n < 4; ++n)
      bfr[n] = __builtin_bit_cast(bf16x8, *(const ushort8v*)&sm.AB[cur][1][boff[n]]);
    __builtin_amdgcn_s_setprio(1);
#pragma unroll
    for (int m = 0; m < 4; ++m)
#pragma unroll
      for (int n = 0; n < 4; ++n)
        acc[m][n] = __builtin_amdgcn_mfma_f32_16x16x32_bf16(af[m], bfr[n], acc[m][n], 0, 0, 0);
    __builtin_amdgcn_s_setprio(0);
  }
  __builtin_amdgcn_s_barrier();  // all waves done reading AB before C reuses LDS

  // Epilogue: bias (+relu), repack C through padded LDS for 16B stores.
#pragma unroll
  for (int m = 0; m < 4; ++m)
#pragma unroll
    for (int n = 0; n < 4; ++n) {
      const int col_l = wn * 64 + n * 16 + fr;
      const float bb = bias[bn * 128 + col_l];
      const int row_l0 = wm * 64 + m * 16 + (fhi << 2);
#pragma unroll
      for (int i = 0; i < 4; ++i) {
        float v = acc[m][n][i] + bb;
        if constexpr (RELU) v = fmaxf(v, 0.f);
        sm.C[(row_l0 + i) * 136 + col_l] = f2b(v);
      }
    }
  __syncthreads();
#pragma unroll
  for (int r8 = 0; r8 < 8; ++r8) {
    const int chunk = r8 * 256 + tid;
    const int row = chunk >> 4;
    const int c8 = (chunk & 15) * 8;
    ushort8v v = *(const ushort8v*)&sm.C[row * 136 + c8];
    *(ushort8v*)&Out[(size_t)(bm * 128 + row) * (size_t)NLD + bn * 128 + c8] = v;
  }
}

// ---------------------------------------------------------------------------
// Vocab-space residual + LayerNorm + gate (f32 math). One wave per vocab row.
// ---------------------------------------------------------------------------
__global__ __launch_bounds__(256) void lnv_kernel(
    const float* __restrict__ emb, const unsigned short* __restrict__ FFv,
    unsigned short* __restrict__ Hv, const float* __restrict__ ln_g,
    const float* __restrict__ ln_b, const float* __restrict__ wg,
    const float* __restrict__ bgp, float* __restrict__ gatev,
    const int* __restrict__ seq, float* __restrict__ hlast) {
  const int lane = threadIdx.x & 63;
  const int w = threadIdx.x >> 6;
  const int v = blockIdx.x * 4 + w;
  const float* er = emb + (size_t)v * ND + lane * 8;
  ushort8v fv = *(const ushort8v*)&FFv[(size_t)v * ND + lane * 8];
  float4 e0 = *(const float4*)er, e1 = *(const float4*)(er + 4);
  float x[8] = {b2f(fv[0]) + e0.x, b2f(fv[1]) + e0.y, b2f(fv[2]) + e0.z, b2f(fv[3]) + e0.w,
                b2f(fv[4]) + e1.x, b2f(fv[5]) + e1.y, b2f(fv[6]) + e1.z, b2f(fv[7]) + e1.w};
  float s = 0.f, sq = 0.f;
#pragma unroll
  for (int j = 0; j < 8; ++j) {
    s += x[j];
    sq += x[j] * x[j];
  }
#pragma unroll
  for (int o = 32; o; o >>= 1) {
    s += __shfl_xor(s, o);
    sq += __shfl_xor(sq, o);
  }
  const float mu = s * (1.f / 512.f);
  const float var = sq * (1.f / 512.f) - mu * mu;
  const float rs = rsqrtf(var + 1e-5f);
  float gd = 0.f;
  float h[8];
  ushort8v hv;
#pragma unroll
  for (int j = 0; j < 8; ++j) {
    const int col = lane * 8 + j;
    h[j] = (x[j] - mu) * rs * ln_g[col] + ln_b[col];
    hv[j] = f2b(h[j]);
    gd += h[j] * wg[col];
  }
  *(ushort8v*)&Hv[(size_t)v * ND + lane * 8] = hv;
#pragma unroll
  for (int o = 32; o; o >>= 1) gd += __shfl_xor(gd, o);
  if (lane == 0) gatev[v] = 1.f / (1.f + expf(-(gd + bgp[0])));
  for (int b = 0; b < NB; ++b) {
    if (seq[b * NT + NT - 1] == v) {
      float* hl = hlast + b * ND + lane * 8;
#pragma unroll
      for (int j = 0; j < 8; ++j) hl[j] = h[j];
    }
  }
}

// ---------------------------------------------------------------------------
// Merged: blocks 0..15 = per-batch top-256 radix select (register keys,
// wave-reduce counts, 1 barrier/bit, packed scan); blocks 16..143 = qpart.
// ---------------------------------------------------------------------------
__global__ __launch_bounds__(256) void topk_qpart_kernel(
    const float* __restrict__ gatev, const int* __restrict__ seq,
    int* __restrict__ topidx, const float* __restrict__ hlast,
    const float* __restrict__ wq, const float* __restrict__ bq,
    float* __restrict__ qpart) {
  __shared__ int wsum[2][4];
  __shared__ unsigned int scanbuf[256];
  const int tid = threadIdx.x;
  if (blockIdx.x >= 16) {
    const int blk = blockIdx.x - 16;
    const int b = blk >> 3, s = blk & 7;
    const int d0 = s * 64;
    float a0 = 0.f, a1 = 0.f;
#pragma unroll 4
    for (int dd = 0; dd < 64; ++dd) {
      const float hv = hlast[b * ND + d0 + dd];
      a0 += hv * wq[(size_t)(d0 + dd) * ND + tid];
      a1 += hv * wq[(size_t)(d0 + dd) * ND + tid + 256];
    }
    if (s == 0) {
      a0 += bq[tid];
      a1 += bq[tid + 256];
    }
    float* qp = qpart + ((size_t)b * 8 + s) * ND;
    qp[tid] = a0;
    qp[tid + 256] = a1;
    return;
  }
  const int b = blockIdx.x;
  const int wv = tid >> 6;
  const int lane = tid & 63;
  const int* sq_ = seq + (size_t)b * NT;
  const int base = tid * 16;
  unsigned int kreg[16];
#pragma unroll
  for (int j = 0; j < 16; ++j)
    kreg[j] = __builtin_bit_cast(unsigned int, gatev[sq_[base + j]]);

  unsigned int K = 0u;
  for (int bit = 31; bit >= 0; --bit) {
    const unsigned int cand = K | (1u << bit);
    int c = 0;
#pragma unroll
    for (int j = 0; j < 16; ++j) c += (kreg[j] >= cand) ? 1 : 0;
#pragma unroll
    for (int o = 32; o; o >>= 1) c += __shfl_xor(c, o);
    const int par = bit & 1;
    if (lane == 0) wsum[par][wv] = c;
    __syncthreads();
    const int tot = wsum[par][0] + wsum[par][1] + wsum[par][2] + wsum[par][3];
    if (tot >= NSLOTS) K = cand;
  }
  int gcnt = 0, ecnt = 0;
#pragma unroll
  for (int j = 0; j < 16; ++j) {
    gcnt += (kreg[j] > K) ? 1 : 0;
    ecnt += (kreg[j] == K) ? 1 : 0;
  }
  __syncthreads();
  scanbuf[tid] = ((unsigned int)gcnt << 16) | (unsigned int)ecnt;
  __syncthreads();
  for (int off = 1; off < 256; off <<= 1) {
    unsigned int v2 = (tid >= off) ? scanbuf[tid - off] : 0u;
    __syncthreads();
    scanbuf[tid] += v2;
    __syncthreads();
  }
  const unsigned int my = scanbuf[tid];
  const unsigned int tot = scanbuf[255];
  const int gi = (int)(my >> 16);
  const int ei = (int)(my & 0xFFFFu);
  const int tot_gt = (int)(tot >> 16);
  int gpos = gi - gcnt;
  int epos = tot_gt + (ei - ecnt);
  int* outp = topidx + b * NSLOTS;
#pragma unroll
  for (int j = 0; j < 16; ++j) {
    if (kreg[j] > K) {
      outp[gpos++] = base + j;
    } else if (kreg[j] == K) {
      if (epos < NSLOTS) outp[epos] = base + j;
      epos++;
    }
  }
}

// ---------------------------------------------------------------------------
// Fused scores + softmax + ctx. 64 blocks = 16 batches x 4 d-chunks of 128.
// ---------------------------------------------------------------------------
__global__ __launch_bounds__(256) void attn_kernel(
    const unsigned short* __restrict__ Hv, const int* __restrict__ seq,
    const float* __restrict__ qpart, const int* __restrict__ topidx,
    float* __restrict__ ctx) {
  __shared__ float qs[512];
  __shared__ float attnv[256];
  __shared__ int idxs[256];
  __shared__ float red[4];
  __shared__ float part[2][128];
  const int blk = blockIdx.x;
  const int b = blk >> 2, dc = blk & 3;
  const int tid = threadIdx.x;
  const int lane = tid & 63, wv = tid >> 6;
  {
    float a0 = 0.f, a1 = 0.f;
#pragma unroll
    for (int s = 0; s < 8; ++s) {
      const float* qp = qpart + ((size_t)b * 8 + s) * ND;
      a0 += qp[tid];
      a1 += qp[tid + 256];
    }
    qs[tid] = a0;
    qs[tid + 256] = a1;
  }
  idxs[tid] = seq[(size_t)b * NT + topidx[b * 256 + tid]];
  __syncthreads();
  const unsigned short* hr = Hv + (size_t)idxs[tid] * ND;
  float sc = 0.f;
  for (int d0 = 0; d0 < 512; d0 += 8) {
    ushort8v hv = *(const ushort8v*)&hr[d0];
#pragma unroll
    for (int j = 0; j < 8; ++j) sc += b2f(hv[j]) * qs[d0 + j];
  }
  float m = sc;
#pragma unroll
  for (int o = 32; o; o >>= 1) m = fmaxf(m, __shfl_xor(m, o));
  if (lane == 0) red[wv] = m;
  __syncthreads();
  m = fmaxf(fmaxf(red[0], red[1]), fmaxf(red[2], red[3]));
  __syncthreads();
  const float e = expf(sc - m);
  float ssum = e;
#pragma unroll
  for (int o = 32; o; o >>= 1) ssum += __shfl_xor(ssum, o);
  if (lane == 0) red[wv] = ssum;
  __syncthreads();
  ssum = red[0] + red[1] + red[2] + red[3];
  attnv[tid] = e / ssum;
  __syncthreads();
  const int d = dc * 128 + (tid & 127);
  const int kh = tid >> 7;
  float c = 0.f;
#pragma unroll 4
  for (int k2 = 0; k2 < 128; ++k2) {
    const int k = kh * 128 + k2;
    c += attnv[k] * b2f(Hv[(size_t)idxs[k] * ND + d]);
  }
  part[kh][tid & 127] = c;
  __syncthreads();
  if (tid < 128) ctx[b * 512 + dc * 128 + tid] = part[0][tid] + part[1][tid];
}

// ---------------------------------------------------------------------------
// Out-projection stage 1: part[s][b][v] = sum_{d in slice s(64)} ctx[b][d]*wo[d][v]
// ---------------------------------------------------------------------------
__global__ __launch_bounds__(256) void out_part_kernel(const float* __restrict__ ctx,
                                                       const float* __restrict__ wo,
                                                       float* __restrict__ part) {
  const int blk = blockIdx.x;
  const int ct = blk % 125, s = blk / 125;
  const int v = ct * 256 + threadIdx.x;
  const int d0 = s * 64;
  const float* wp = wo + (size_t)d0 * NV + v;
  float acc[16] = {};
#pragma unroll 4
  for (int dd = 0; dd < 64; ++dd) {
    const float wv = wp[(size_t)dd * NV];
#pragma unroll
    for (int bb = 0; bb < 16; ++bb) acc[bb] += ctx[bb * ND + d0 + dd] * wv;
  }
  float* pp = part + (size_t)s * NB * NV + v;
#pragma unroll
  for (int bb = 0; bb < 16; ++bb) pp[(size_t)bb * NV] = acc[bb];
}

// ---------------------------------------------------------------------------
// Out-projection stage 2: out[b][v] = sum_s part[s][b][v] + bo[v]
// ---------------------------------------------------------------------------
__global__ __launch_bounds__(256) void out_reduce_kernel(const float* __restrict__ part,
                                                         const float* __restrict__ bo,
                                                         float* __restrict__ out) {
  const int i = blockIdx.x * 256 + threadIdx.x;
  const int b = i / NV;
  const int v = i - b * NV;
  float a = bo[v];
#pragma unroll
  for (int s = 0; s < 8; ++s) a += part[(size_t)s * NB * NV + i];
  out[i] = a;
}

// ---------------------------------------------------------------------------
// Workspace layout (vocab-space; total ~181 MiB):
//   A1v   @ 0        : 32000x1024 bf16 = 62.5 MiB
//   FFv   @ 64 MiB   : 31.25 MiB
//   embb  @ 96 MiB   : 31.25 MiB
//   Hv    @ 128 MiB  : 31.25 MiB
//   part  @ 160 MiB  : 16.4 MB
//   w1t   @ 177 MiB, w2t @ 178 MiB, smalls @ 180 MiB
// ---------------------------------------------------------------------------
extern "C" void kernel_launch(void* const* d_in, const int* in_sizes, int n_in,
                              void* d_out, int out_size, void* d_ws, size_t ws_size,
                              hipStream_t stream) {
  const int* seq = (const int*)d_in[0];
  const float* emb = (const float*)d_in[1];
  const float* w1 = (const float*)d_in[2];
  const float* b1 = (const float*)d_in[3];
  const float* w2 = (const float*)d_in[4];
  const float* b2 = (const float*)d_in[5];
  const float* ln_g = (const float*)d_in[6];
  const float* ln_b = (const float*)d_in[7];
  const float* wg = (const float*)d_in[8];
  const float* bg = (const float*)d_in[9];
  const float* wq = (const float*)d_in[10];
  const float* bq = (const float*)d_in[11];
  const float* wo = (const float*)d_in[12];
  const float* bo = (const float*)d_in[13];
  float* out = (float*)d_out;

  char* ws = (char*)d_ws;
  unsigned short* A1v = (unsigned short*)ws;                        // 62.5 MiB
  unsigned short* FFv = (unsigned short*)(ws + ((size_t)64 << 20)); // 31.25 MiB
  unsigned short* embb = (unsigned short*)(ws + ((size_t)96 << 20));
  unsigned short* Hv = (unsigned short*)(ws + ((size_t)128 << 20));
  float* part = (float*)(ws + ((size_t)160 << 20));                 // 16.4 MB
  unsigned short* w1t = (unsigned short*)(ws + ((size_t)177 << 20));
  unsigned short* w2t = (unsigned short*)(ws + ((size_t)178 << 20));
  char* sb = ws + ((size_t)180 << 20);
  float* gatev = (float*)sb;                                        // 128 KiB
  int* topidx = (int*)(sb + 131072);                                // 16 KiB
  float* hlast = (float*)(sb + 131072 + 16384);                     // 32 KiB
  float* ctxbuf = (float*)(sb + 131072 + 16384 + 32768);            // 32 KiB
  float* qpart = (float*)(sb + 131072 + 16384 + 65536);             // 256 KiB

  cvtwt_kernel<<<12096, 256, 0, stream>>>(emb, embb, w1, w2, w1t, w2t);
  // FF over vocab rows (32000 = 250 x 128)
  gemm128_kernel<512, 1024, 8, true>
      <<<2000, 256, 0, stream>>>(embb, w1t, b1, A1v);
  gemm128_kernel<1024, 512, 4, false>
      <<<1000, 256, 0, stream>>>(A1v, w2t, b2, FFv);
  lnv_kernel<<<8000, 256, 0, stream>>>(emb, FFv, Hv, ln_g, ln_b, wg, bg, gatev, seq, hlast);
  topk_qpart_kernel<<<144, 256, 0, stream>>>(gatev, seq, topidx, hlast, wq, bq, qpart);
  attn_kernel<<<64, 256, 0, stream>>>(Hv, seq, qpart, topidx, ctxbuf);
  out_part_kernel<<<1000, 256, 0, stream>>>(ctxbuf, wo, part);
  out_reduce_kernel<<<2000, 256, 0, stream>>>(part, bo, out);
}

// Round 14
// 199.419 us; speedup vs baseline: 1.0347x; 1.0347x over previous
//
#include <hip/hip_runtime.h>

typedef __bf16 bf16x8 __attribute__((ext_vector_type(8)));
typedef float f32x4 __attribute__((ext_vector_type(4)));
typedef unsigned short ushort8v __attribute__((ext_vector_type(8)));

#define NB 16
#define NT 4096
#define NV 32000
#define ND 512
#define NH 1024
#define NSLOTS 256

__device__ __forceinline__ float b2f(unsigned short u) {
  unsigned int x = ((unsigned int)u) << 16;
  return __builtin_bit_cast(float, x);
}
__device__ __forceinline__ unsigned short f2b(float f) {
  unsigned int x = __builtin_bit_cast(unsigned int, f);
  unsigned int r = (x + 0x7FFFu + ((x >> 16) & 1u)) >> 16;
  return (unsigned short)r;
}

#define GLOAD_LDS16(g, l)                                                              \
  __builtin_amdgcn_global_load_lds((const __attribute__((address_space(1))) void*)(g), \
                                   (__attribute__((address_space(3))) void*)(l), 16, 0, 0)

// ---------------------------------------------------------------------------
// Fused elementwise prep: emb f32->bf16 (blocks <8000) and w1/w2 transpose+cvt.
// ---------------------------------------------------------------------------
__global__ __launch_bounds__(256) void cvtwt_kernel(
    const float* __restrict__ emb, unsigned short* __restrict__ embb,
    const float* __restrict__ w1, const float* __restrict__ w2,
    unsigned short* __restrict__ w1t, unsigned short* __restrict__ w2t) {
  const int blk = blockIdx.x;
  if (blk < 8000) {
    const long base = ((long)blk * 256 + threadIdx.x) * 8;
    float4 a = *(const float4*)&emb[base];
    float4 b = *(const float4*)&emb[base + 4];
    ushort8v o;
    o[0] = f2b(a.x); o[1] = f2b(a.y); o[2] = f2b(a.z); o[3] = f2b(a.w);
    o[4] = f2b(b.x); o[5] = f2b(b.y); o[6] = f2b(b.z); o[7] = f2b(b.w);
    *(ushort8v*)&embb[base] = o;
  } else {
    const int i = (blk - 8000) * 256 + threadIdx.x;
    if (i < ND * NH) {
      const int n = i >> 9, k = i & 511;
      w1t[i] = f2b(w1[k * NH + n]);
    } else {
      const int j = i - ND * NH;
      const int n = j >> 10, k = j & 1023;
      w2t[j] = f2b(w2[k * ND + n]);
    }
  }
}

// ---------------------------------------------------------------------------
// 128x128 bf16 MFMA GEMM over VOCAB rows (M = 32000 = 250 tiles): BK=32,
// 3-deep buffer pipeline with counted vmcnt, XOR-swizzled LDS, XCD block
// swizzle (grid % 8 == 0), setprio around MFMA cluster. 4 waves (2x2),
// 48 KiB LDS -> 3 blocks/CU inter-block pipe overlap. (r6 structure, 600+ TF)
// ---------------------------------------------------------------------------
template <int KDIM, int NLD, int NBN, bool RELU>
__global__ __launch_bounds__(256) void gemm128_kernel(
    const unsigned short* __restrict__ Abase, const unsigned short* __restrict__ Bt,
    const float* __restrict__ bias, unsigned short* __restrict__ Out) {
  __shared__ union {
    unsigned short AB[3][2][128 * 32];  // [buf][A/B][row*32 + chunk*8]
    unsigned short C[128 * 136];        // padded epilogue tile
  } sm;
  const int tid = threadIdx.x;
  const int lane = tid & 63;
  const int w = tid >> 6;

  const int id = blockIdx.x;
  const int swz = (id & 7) * (gridDim.x >> 3) + (id >> 3);
  const int bm = swz / NBN;
  const int bn = swz % NBN;

  const int wm = w >> 1, wn = w & 1;

  const int rgrp = lane >> 2;
  const int schunk = (lane & 3) ^ ((lane >> 3) & 3);
  const unsigned short* aptr[2];
  const unsigned short* bptr[2];
#pragma unroll
  for (int r = 0; r < 2; ++r) {
    const int grp = w * 2 + r;
    const int arow = bm * 128 + grp * 16 + rgrp;
    aptr[r] = Abase + (size_t)arow * (size_t)KDIM + schunk * 8;
    const int brow = bn * 128 + grp * 16 + rgrp;
    bptr[r] = Bt + (size_t)brow * (size_t)KDIM + schunk * 8;
  }

  const int fr = lane & 15;
  const int fhi = lane >> 4;
  const int fsw = (fr >> 1) & 3;
  const int fchunk = (fhi ^ fsw) * 8;
  int aoff[4], boff[4];
#pragma unroll
  for (int m = 0; m < 4; ++m) aoff[m] = (wm * 64 + m * 16 + fr) * 32 + fchunk;
#pragma unroll
  for (int n = 0; n < 4; ++n) boff[n] = (wn * 64 + n * 16 + fr) * 32 + fchunk;

  f32x4 acc[4][4] = {};

  auto stage = [&](int buf, int kt) {
#pragma unroll
    for (int r = 0; r < 2; ++r) {
      const int grp = w * 2 + r;
      GLOAD_LDS16(aptr[r] + kt * 32, &sm.AB[buf][0][grp * 512]);
      GLOAD_LDS16(bptr[r] + kt * 32, &sm.AB[buf][1][grp * 512]);
    }
  };

  constexpr int NKT = KDIM / 32;
  stage(0, 0);
  stage(1, 1);
  for (int kt = 0; kt < NKT; ++kt) {
    if (kt + 1 < NKT)
      asm volatile("s_waitcnt vmcnt(4)" ::: "memory");
    else
      asm volatile("s_waitcnt vmcnt(0)" ::: "memory");
    __builtin_amdgcn_s_barrier();
    if (kt + 2 < NKT) stage((kt + 2) % 3, kt + 2);
    const int cur = kt % 3;
    bf16x8 af[4], bfr[4];
#pragma unroll
    for (int m = 0; m < 4; ++m)
      af[m] = __builtin_bit_cast(bf16x8, *(const ushort8v*)&sm.AB[cur][0][aoff[m]]);
#pragma unroll
    for (int n = 0; n < 4; ++n)
      bfr[n] = __builtin_bit_cast(bf16x8, *(const ushort8v*)&sm.AB[cur][1][boff[n]]);
    __builtin_amdgcn_s_setprio(1);
#pragma unroll
    for (int m = 0; m < 4; ++m)
#pragma unroll
      for (int n = 0; n < 4; ++n)
        acc[m][n] = __builtin_amdgcn_mfma_f32_16x16x32_bf16(af[m], bfr[n], acc[m][n], 0, 0, 0);
    __builtin_amdgcn_s_setprio(0);
  }
  __builtin_amdgcn_s_barrier();

#pragma unroll
  for (int m = 0; m < 4; ++m)
#pragma unroll
    for (int n = 0; n < 4; ++n) {
      const int col_l = wn * 64 + n * 16 + fr;
      const float bb = bias[bn * 128 + col_l];
      const int row_l0 = wm * 64 + m * 16 + (fhi << 2);
#pragma unroll
      for (int i = 0; i < 4; ++i) {
        float v = acc[m][n][i] + bb;
        if constexpr (RELU) v = fmaxf(v, 0.f);
        sm.C[(row_l0 + i) * 136 + col_l] = f2b(v);
      }
    }
  __syncthreads();
#pragma unroll
  for (int r8 = 0; r8 < 8; ++r8) {
    const int chunk = r8 * 256 + tid;
    const int row = chunk >> 4;
    const int c8 = (chunk & 15) * 8;
    ushort8v v = *(const ushort8v*)&sm.C[row * 136 + c8];
    *(ushort8v*)&Out[(size_t)(bm * 128 + row) * (size_t)NLD + bn * 128 + c8] = v;
  }
}

// ---------------------------------------------------------------------------
// Vocab-space residual + LayerNorm + gate (f32 math). One wave per vocab row.
// ---------------------------------------------------------------------------
__global__ __launch_bounds__(256) void lnv_kernel(
    const float* __restrict__ emb, const unsigned short* __restrict__ FFv,
    unsigned short* __restrict__ Hv, const float* __restrict__ ln_g,
    const float* __restrict__ ln_b, const float* __restrict__ wg,
    const float* __restrict__ bgp, float* __restrict__ gatev,
    const int* __restrict__ seq, float* __restrict__ hlast) {
  const int lane = threadIdx.x & 63;
  const int w = threadIdx.x >> 6;
  const int v = blockIdx.x * 4 + w;
  const float* er = emb + (size_t)v * ND + lane * 8;
  ushort8v fv = *(const ushort8v*)&FFv[(size_t)v * ND + lane * 8];
  float4 e0 = *(const float4*)er, e1 = *(const float4*)(er + 4);
  float x[8] = {b2f(fv[0]) + e0.x, b2f(fv[1]) + e0.y, b2f(fv[2]) + e0.z, b2f(fv[3]) + e0.w,
                b2f(fv[4]) + e1.x, b2f(fv[5]) + e1.y, b2f(fv[6]) + e1.z, b2f(fv[7]) + e1.w};
  float s = 0.f, sq = 0.f;
#pragma unroll
  for (int j = 0; j < 8; ++j) {
    s += x[j];
    sq += x[j] * x[j];
  }
#pragma unroll
  for (int o = 32; o; o >>= 1) {
    s += __shfl_xor(s, o);
    sq += __shfl_xor(sq, o);
  }
  const float mu = s * (1.f / 512.f);
  const float var = sq * (1.f / 512.f) - mu * mu;
  const float rs = rsqrtf(var + 1e-5f);
  float gd = 0.f;
  float h[8];
  ushort8v hv;
#pragma unroll
  for (int j = 0; j < 8; ++j) {
    const int col = lane * 8 + j;
    h[j] = (x[j] - mu) * rs * ln_g[col] + ln_b[col];
    hv[j] = f2b(h[j]);
    gd += h[j] * wg[col];
  }
  *(ushort8v*)&Hv[(size_t)v * ND + lane * 8] = hv;
#pragma unroll
  for (int o = 32; o; o >>= 1) gd += __shfl_xor(gd, o);
  if (lane == 0) gatev[v] = 1.f / (1.f + expf(-(gd + bgp[0])));
  for (int b = 0; b < NB; ++b) {
    if (seq[b * NT + NT - 1] == v) {
      float* hl = hlast + b * ND + lane * 8;
#pragma unroll
      for (int j = 0; j < 8; ++j) hl[j] = h[j];
    }
  }
}

// ---------------------------------------------------------------------------
// Merged: blocks 0..15 = per-batch top-256 radix select (register keys,
// wave-reduce counts, 1 barrier/bit, packed scan; bits 31,30 provably zero
// for sigmoid outputs < 1 so the loop starts at bit 29); blocks 16..143 =
// qpart slices.
// ---------------------------------------------------------------------------
__global__ __launch_bounds__(256) void topk_qpart_kernel(
    const float* __restrict__ gatev, const int* __restrict__ seq,
    int* __restrict__ topidx, const float* __restrict__ hlast,
    const float* __restrict__ wq, const float* __restrict__ bq,
    float* __restrict__ qpart) {
  __shared__ int wsum[2][4];
  __shared__ unsigned int scanbuf[256];
  const int tid = threadIdx.x;
  if (blockIdx.x >= 16) {
    const int blk = blockIdx.x - 16;
    const int b = blk >> 3, s = blk & 7;
    const int d0 = s * 64;
    float a0 = 0.f, a1 = 0.f;
#pragma unroll 4
    for (int dd = 0; dd < 64; ++dd) {
      const float hv = hlast[b * ND + d0 + dd];
      a0 += hv * wq[(size_t)(d0 + dd) * ND + tid];
      a1 += hv * wq[(size_t)(d0 + dd) * ND + tid + 256];
    }
    if (s == 0) {
      a0 += bq[tid];
      a1 += bq[tid + 256];
    }
    float* qp = qpart + ((size_t)b * 8 + s) * ND;
    qp[tid] = a0;
    qp[tid + 256] = a1;
    return;
  }
  const int b = blockIdx.x;
  const int wv = tid >> 6;
  const int lane = tid & 63;
  const int* sq_ = seq + (size_t)b * NT;
  const int base = tid * 16;
  unsigned int kreg[16];
#pragma unroll
  for (int j = 0; j < 16; ++j)
    kreg[j] = __builtin_bit_cast(unsigned int, gatev[sq_[base + j]]);

  unsigned int K = 0u;
  for (int bit = 29; bit >= 0; --bit) {
    const unsigned int cand = K | (1u << bit);
    int c = 0;
#pragma unroll
    for (int j = 0; j < 16; ++j) c += (kreg[j] >= cand) ? 1 : 0;
#pragma unroll
    for (int o = 32; o; o >>= 1) c += __shfl_xor(c, o);
    const int par = bit & 1;
    if (lane == 0) wsum[par][wv] = c;
    __syncthreads();
    const int tot = wsum[par][0] + wsum[par][1] + wsum[par][2] + wsum[par][3];
    if (tot >= NSLOTS) K = cand;
  }
  int gcnt = 0, ecnt = 0;
#pragma unroll
  for (int j = 0; j < 16; ++j) {
    gcnt += (kreg[j] > K) ? 1 : 0;
    ecnt += (kreg[j] == K) ? 1 : 0;
  }
  __syncthreads();
  scanbuf[tid] = ((unsigned int)gcnt << 16) | (unsigned int)ecnt;
  __syncthreads();
  for (int off = 1; off < 256; off <<= 1) {
    unsigned int v2 = (tid >= off) ? scanbuf[tid - off] : 0u;
    __syncthreads();
    scanbuf[tid] += v2;
    __syncthreads();
  }
  const unsigned int my = scanbuf[tid];
  const unsigned int tot = scanbuf[255];
  const int gi = (int)(my >> 16);
  const int ei = (int)(my & 0xFFFFu);
  const int tot_gt = (int)(tot >> 16);
  int gpos = gi - gcnt;
  int epos = tot_gt + (ei - ecnt);
  int* outp = topidx + b * NSLOTS;
#pragma unroll
  for (int j = 0; j < 16; ++j) {
    if (kreg[j] > K) {
      outp[gpos++] = base + j;
    } else if (kreg[j] == K) {
      if (epos < NSLOTS) outp[epos] = base + j;
      epos++;
    }
  }
}

// ---------------------------------------------------------------------------
// Fused scores + softmax + ctx. 64 blocks = 16 batches x 4 d-chunks of 128.
// ---------------------------------------------------------------------------
__global__ __launch_bounds__(256) void attn_kernel(
    const unsigned short* __restrict__ Hv, const int* __restrict__ seq,
    const float* __restrict__ qpart, const int* __restrict__ topidx,
    float* __restrict__ ctx) {
  __shared__ float qs[512];
  __shared__ float attnv[256];
  __shared__ int idxs[256];
  __shared__ float red[4];
  __shared__ float part[2][128];
  const int blk = blockIdx.x;
  const int b = blk >> 2, dc = blk & 3;
  const int tid = threadIdx.x;
  const int lane = tid & 63, wv = tid >> 6;
  {
    float a0 = 0.f, a1 = 0.f;
#pragma unroll
    for (int s = 0; s < 8; ++s) {
      const float* qp = qpart + ((size_t)b * 8 + s) * ND;
      a0 += qp[tid];
      a1 += qp[tid + 256];
    }
    qs[tid] = a0;
    qs[tid + 256] = a1;
  }
  idxs[tid] = seq[(size_t)b * NT + topidx[b * 256 + tid]];
  __syncthreads();
  const unsigned short* hr = Hv + (size_t)idxs[tid] * ND;
  float sc = 0.f;
  for (int d0 = 0; d0 < 512; d0 += 8) {
    ushort8v hv = *(const ushort8v*)&hr[d0];
#pragma unroll
    for (int j = 0; j < 8; ++j) sc += b2f(hv[j]) * qs[d0 + j];
  }
  float m = sc;
#pragma unroll
  for (int o = 32; o; o >>= 1) m = fmaxf(m, __shfl_xor(m, o));
  if (lane == 0) red[wv] = m;
  __syncthreads();
  m = fmaxf(fmaxf(red[0], red[1]), fmaxf(red[2], red[3]));
  __syncthreads();
  const float e = expf(sc - m);
  float ssum = e;
#pragma unroll
  for (int o = 32; o; o >>= 1) ssum += __shfl_xor(ssum, o);
  if (lane == 0) red[wv] = ssum;
  __syncthreads();
  ssum = red[0] + red[1] + red[2] + red[3];
  attnv[tid] = e / ssum;
  __syncthreads();
  const int d = dc * 128 + (tid & 127);
  const int kh = tid >> 7;
  float c = 0.f;
#pragma unroll 4
  for (int k2 = 0; k2 < 128; ++k2) {
    const int k = kh * 128 + k2;
    c += attnv[k] * b2f(Hv[(size_t)idxs[k] * ND + d]);
  }
  part[kh][tid & 127] = c;
  __syncthreads();
  if (tid < 128) ctx[b * 512 + dc * 128 + tid] = part[0][tid] + part[1][tid];
}

// ---------------------------------------------------------------------------
// Fused out-projection (no partial round-trip): 1000 blocks x 32 vocab cols.
// 256 threads = 32 cols x 8 D-groups of 64; ctx in LDS (broadcast reads);
// cross-group reduce via LDS. Summation order identical to the old
// out_part(64-slice, ascending dd) + out_reduce(bo first, slices ascending).
// ---------------------------------------------------------------------------
__global__ __launch_bounds__(256) void out_fused_kernel(const float* __restrict__ ctx,
                                                        const float* __restrict__ wo,
                                                        const float* __restrict__ bo,
                                                        float* __restrict__ out) {
  __shared__ float cs[16 * 512];
  __shared__ float red[8][16][32];
  const int tid = threadIdx.x;
  const int c = tid & 31, g = tid >> 5;
  const int v0 = blockIdx.x * 32;
  for (int i = tid; i < 16 * 512; i += 256) cs[i] = ctx[i];
  __syncthreads();
  const int d0 = g * 64;
  float acc[16] = {};
  const float* wp = wo + (size_t)d0 * NV + v0 + c;
#pragma unroll 4
  for (int dd = 0; dd < 64; ++dd) {
    const float wv = wp[(size_t)dd * NV];
#pragma unroll
    for (int bb = 0; bb < 16; ++bb) acc[bb] += cs[bb * 512 + d0 + dd] * wv;
  }
#pragma unroll
  for (int bb = 0; bb < 16; ++bb) red[g][bb][c] = acc[bb];
  __syncthreads();
  for (int i = tid; i < 512; i += 256) {
    const int bb = i >> 5, cc = i & 31;
    float a = bo[v0 + cc];
#pragma unroll
    for (int gg = 0; gg < 8; ++gg) a += red[gg][bb][cc];
    out[(size_t)bb * NV + v0 + cc] = a;
  }
}

// ---------------------------------------------------------------------------
// Workspace layout (vocab-space; total ~181 MiB):
//   A1v   @ 0        : 32000x1024 bf16 = 62.5 MiB
//   FFv   @ 64 MiB   : 31.25 MiB
//   embb  @ 96 MiB   : 31.25 MiB
//   Hv    @ 128 MiB  : 31.25 MiB
//   w1t   @ 177 MiB, w2t @ 178 MiB, smalls @ 180 MiB
// ---------------------------------------------------------------------------
extern "C" void kernel_launch(void* const* d_in, const int* in_sizes, int n_in,
                              void* d_out, int out_size, void* d_ws, size_t ws_size,
                              hipStream_t stream) {
  const int* seq = (const int*)d_in[0];
  const float* emb = (const float*)d_in[1];
  const float* w1 = (const float*)d_in[2];
  const float* b1 = (const float*)d_in[3];
  const float* w2 = (const float*)d_in[4];
  const float* b2 = (const float*)d_in[5];
  const float* ln_g = (const float*)d_in[6];
  const float* ln_b = (const float*)d_in[7];
  const float* wg = (const float*)d_in[8];
  const float* bg = (const float*)d_in[9];
  const float* wq = (const float*)d_in[10];
  const float* bq = (const float*)d_in[11];
  const float* wo = (const float*)d_in[12];
  const float* bo = (const float*)d_in[13];
  float* out = (float*)d_out;

  char* ws = (char*)d_ws;
  unsigned short* A1v = (unsigned short*)ws;                        // 62.5 MiB
  unsigned short* FFv = (unsigned short*)(ws + ((size_t)64 << 20)); // 31.25 MiB
  unsigned short* embb = (unsigned short*)(ws + ((size_t)96 << 20));
  unsigned short* Hv = (unsigned short*)(ws + ((size_t)128 << 20));
  unsigned short* w1t = (unsigned short*)(ws + ((size_t)177 << 20));
  unsigned short* w2t = (unsigned short*)(ws + ((size_t)178 << 20));
  char* sb = ws + ((size_t)180 << 20);
  float* gatev = (float*)sb;                                        // 128 KiB
  int* topidx = (int*)(sb + 131072);                                // 16 KiB
  float* hlast = (float*)(sb + 131072 + 16384);                     // 32 KiB
  float* ctxbuf = (float*)(sb + 131072 + 16384 + 32768);            // 32 KiB
  float* qpart = (float*)(sb + 131072 + 16384 + 65536);             // 256 KiB

  cvtwt_kernel<<<12096, 256, 0, stream>>>(emb, embb, w1, w2, w1t, w2t);
  gemm128_kernel<512, 1024, 8, true>
      <<<2000, 256, 0, stream>>>(embb, w1t, b1, A1v);
  gemm128_kernel<1024, 512, 4, false>
      <<<1000, 256, 0, stream>>>(A1v, w2t, b2, FFv);
  lnv_kernel<<<8000, 256, 0, stream>>>(emb, FFv, Hv, ln_g, ln_b, wg, bg, gatev, seq, hlast);
  topk_qpart_kernel<<<144, 256, 0, stream>>>(gatev, seq, topidx, hlast, wq, bq, qpart);
  attn_kernel<<<64, 256, 0, stream>>>(Hv, seq, qpart, topidx, ctxbuf);
  out_fused_kernel<<<1000, 256, 0, stream>>>(ctxbuf, wo, bo, out);
}

// Round 15
// 183.884 us; speedup vs baseline: 1.1222x; 1.0845x over previous
//
#include <hip/hip_runtime.h>

typedef __bf16 bf16x8 __attribute__((ext_vector_type(8)));
typedef float f32x4 __attribute__((ext_vector_type(4)));
typedef unsigned short ushort8v __attribute__((ext_vector_type(8)));

#define NB 16
#define NT 4096
#define NV 32000
#define ND 512
#define NH 1024
#define NSLOTS 256

__device__ __forceinline__ float b2f(unsigned short u) {
  unsigned int x = ((unsigned int)u) << 16;
  return __builtin_bit_cast(float, x);
}
__device__ __forceinline__ unsigned short f2b(float f) {
  unsigned int x = __builtin_bit_cast(unsigned int, f);
  unsigned int r = (x + 0x7FFFu + ((x >> 16) & 1u)) >> 16;
  return (unsigned short)r;
}

#define GLOAD_LDS16(g, l)                                                              \
  __builtin_amdgcn_global_load_lds((const __attribute__((address_space(1))) void*)(g), \
                                   (__attribute__((address_space(3))) void*)(l), 16, 0, 0)
#define BARRIER() asm volatile("s_barrier" ::: "memory")
#define VMCNT(n) asm volatile("s_waitcnt vmcnt(" #n ")" ::: "memory")

// ---------------------------------------------------------------------------
// Fused elementwise prep: emb f32->bf16 (blocks <8000) and w1/w2 transpose+cvt.
// ---------------------------------------------------------------------------
__global__ __launch_bounds__(256) void cvtwt_kernel(
    const float* __restrict__ emb, unsigned short* __restrict__ embb,
    const float* __restrict__ w1, const float* __restrict__ w2,
    unsigned short* __restrict__ w1t, unsigned short* __restrict__ w2t) {
  const int blk = blockIdx.x;
  if (blk < 8000) {
    const long base = ((long)blk * 256 + threadIdx.x) * 8;
    float4 a = *(const float4*)&emb[base];
    float4 b = *(const float4*)&emb[base + 4];
    ushort8v o;
    o[0] = f2b(a.x); o[1] = f2b(a.y); o[2] = f2b(a.z); o[3] = f2b(a.w);
    o[4] = f2b(b.x); o[5] = f2b(b.y); o[6] = f2b(b.z); o[7] = f2b(b.w);
    *(ushort8v*)&embb[base] = o;
  } else {
    const int i = (blk - 8000) * 256 + threadIdx.x;
    if (i < ND * NH) {
      const int n = i >> 9, k = i & 511;
      w1t[i] = f2b(w1[k * NH + n]);
    } else {
      const int j = i - ND * NH;
      const int n = j >> 10, k = j & 1023;
      w2t[j] = f2b(w2[k * ND + n]);
    }
  }
}

// ---------------------------------------------------------------------------
// 128x128 bf16 MFMA GEMM (gemm1 over vocab rows, M = 32000): BK=32, 3-deep
// buffer pipeline with counted vmcnt, XOR-swizzled LDS, XCD block swizzle
// (grid % 8 == 0), setprio. 4 waves (2x2), 48 KiB LDS -> 3 blocks/CU.
// ---------------------------------------------------------------------------
template <int KDIM, int NLD, int NBN, bool RELU>
__global__ __launch_bounds__(256) void gemm128_kernel(
    const unsigned short* __restrict__ Abase, const unsigned short* __restrict__ Bt,
    const float* __restrict__ bias, unsigned short* __restrict__ Out) {
  __shared__ union {
    unsigned short AB[3][2][128 * 32];
    unsigned short C[128 * 136];
  } sm;
  const int tid = threadIdx.x;
  const int lane = tid & 63;
  const int w = tid >> 6;

  const int id = blockIdx.x;
  const int swz = (id & 7) * (gridDim.x >> 3) + (id >> 3);
  const int bm = swz / NBN;
  const int bn = swz % NBN;

  const int wm = w >> 1, wn = w & 1;

  const int rgrp = lane >> 2;
  const int schunk = (lane & 3) ^ ((lane >> 3) & 3);
  const unsigned short* aptr[2];
  const unsigned short* bptr[2];
#pragma unroll
  for (int r = 0; r < 2; ++r) {
    const int grp = w * 2 + r;
    const int arow = bm * 128 + grp * 16 + rgrp;
    aptr[r] = Abase + (size_t)arow * (size_t)KDIM + schunk * 8;
    const int brow = bn * 128 + grp * 16 + rgrp;
    bptr[r] = Bt + (size_t)brow * (size_t)KDIM + schunk * 8;
  }

  const int fr = lane & 15;
  const int fhi = lane >> 4;
  const int fsw = (fr >> 1) & 3;
  const int fchunk = (fhi ^ fsw) * 8;
  int aoff[4], boff[4];
#pragma unroll
  for (int m = 0; m < 4; ++m) aoff[m] = (wm * 64 + m * 16 + fr) * 32 + fchunk;
#pragma unroll
  for (int n = 0; n < 4; ++n) boff[n] = (wn * 64 + n * 16 + fr) * 32 + fchunk;

  f32x4 acc[4][4] = {};

  auto stage = [&](int buf, int kt) {
#pragma unroll
    for (int r = 0; r < 2; ++r) {
      const int grp = w * 2 + r;
      GLOAD_LDS16(aptr[r] + kt * 32, &sm.AB[buf][0][grp * 512]);
      GLOAD_LDS16(bptr[r] + kt * 32, &sm.AB[buf][1][grp * 512]);
    }
  };

  constexpr int NKT = KDIM / 32;
  stage(0, 0);
  stage(1, 1);
  for (int kt = 0; kt < NKT; ++kt) {
    if (kt + 1 < NKT)
      VMCNT(4);
    else
      VMCNT(0);
    __builtin_amdgcn_s_barrier();
    if (kt + 2 < NKT) stage((kt + 2) % 3, kt + 2);
    const int cur = kt % 3;
    bf16x8 af[4], bfr[4];
#pragma unroll
    for (int m = 0; m < 4; ++m)
      af[m] = __builtin_bit_cast(bf16x8, *(const ushort8v*)&sm.AB[cur][0][aoff[m]]);
#pragma unroll
    for (int n = 0; n < 4; ++n)
      bfr[n] = __builtin_bit_cast(bf16x8, *(const ushort8v*)&sm.AB[cur][1][boff[n]]);
    __builtin_amdgcn_s_setprio(1);
#pragma unroll
    for (int m = 0; m < 4; ++m)
#pragma unroll
      for (int n = 0; n < 4; ++n)
        acc[m][n] = __builtin_amdgcn_mfma_f32_16x16x32_bf16(af[m], bfr[n], acc[m][n], 0, 0, 0);
    __builtin_amdgcn_s_setprio(0);
  }
  __builtin_amdgcn_s_barrier();

#pragma unroll
  for (int m = 0; m < 4; ++m)
#pragma unroll
    for (int n = 0; n < 4; ++n) {
      const int col_l = wn * 64 + n * 16 + fr;
      const float bb = bias[bn * 128 + col_l];
      const int row_l0 = wm * 64 + m * 16 + (fhi << 2);
#pragma unroll
      for (int i = 0; i < 4; ++i) {
        float v = acc[m][n][i] + bb;
        if constexpr (RELU) v = fmaxf(v, 0.f);
        sm.C[(row_l0 + i) * 136 + col_l] = f2b(v);
      }
    }
  __syncthreads();
#pragma unroll
  for (int r8 = 0; r8 < 8; ++r8) {
    const int chunk = r8 * 256 + tid;
    const int row = chunk >> 4;
    const int c8 = (chunk & 15) * 8;
    ushort8v v = *(const ushort8v*)&sm.C[row * 136 + c8];
    *(ushort8v*)&Out[(size_t)(bm * 128 + row) * (size_t)NLD + bn * 128 + c8] = v;
  }
}

// ---------------------------------------------------------------------------
// Fused gemm2 + residual + LayerNorm + gate. 250 blocks x 512 threads.
// Tile 128x512 (full row), 8 waves (2M x 4N, per-wave 64x128), BK=32,
// 3-deep counted-vmcnt pipeline (5 loads/thread/stage -> vmcnt(5)),
// (row>>1)&3 XOR chunk swizzle (r6-verified). Epilogue: acc + b2 rounded to
// bf16 into LDS C tile (bits identical to the old FFv), then the verbatim
// lnv body per row (64-lane rows, identical shfl trees) -> Hv, gatev, hlast.
// ---------------------------------------------------------------------------
__global__ __launch_bounds__(512, 2) void gemm2ln_kernel(
    const unsigned short* __restrict__ A1v, const unsigned short* __restrict__ w2t,
    const float* __restrict__ b2, const float* __restrict__ emb,
    const float* __restrict__ ln_g, const float* __restrict__ ln_b,
    const float* __restrict__ wg, const float* __restrict__ bgp,
    unsigned short* __restrict__ Hv, float* __restrict__ gatev,
    const int* __restrict__ seq, float* __restrict__ hlast) {
  extern __shared__ unsigned short sm2[];  // 3 bufs x 20480 shorts | C [128][516]
  const int tid = threadIdx.x;
  const int lane = tid & 63;
  const int w = tid >> 6;   // 0..7
  const int wm = w >> 2;    // 0..1
  const int wn = w & 3;     // 0..3

  // m204 bijective XCD swizzle (250 blocks)
  const int id = blockIdx.x, nwg = gridDim.x;
  const int q = nwg >> 3, r = nwg & 7;
  const int xcd = id & 7;
  const int bm = ((xcd < r) ? xcd * (q + 1) : r * (q + 1) + (xcd - r) * q) + (id >> 3);

  // Staging: A tile 128x32 (512 chunks, 1/thread), B tile 512x32 (2048, 4/thread).
  // LDS slot (row,c) holds global chunk c ^ ((row>>1)&3).
  const int arow = tid >> 2;
  const int acol = (tid & 3) ^ ((arow >> 1) & 3);
  const unsigned short* aptr = A1v + (size_t)(bm * 128 + arow) * NH + acol * 8;
  const unsigned short* bptr[4];
#pragma unroll
  for (int j = 0; j < 4; ++j) {
    const int c = j * 512 + tid;
    const int brow = c >> 2;
    const int bcol = (c & 3) ^ ((brow >> 1) & 3);
    bptr[j] = w2t + (size_t)brow * NH + bcol * 8;
  }

  const int fr = lane & 15;
  const int fhi = lane >> 4;
  const int fsw = (fr >> 1) & 3;
  const int fchunk = (fhi ^ fsw) * 8;
  int aoff[4], boff[8];
#pragma unroll
  for (int m = 0; m < 4; ++m) aoff[m] = (wm * 64 + m * 16 + fr) * 32 + fchunk;
#pragma unroll
  for (int n = 0; n < 8; ++n) boff[n] = 4096 + (wn * 128 + n * 16 + fr) * 32 + fchunk;

  f32x4 acc[4][8] = {};

  auto stage = [&](int buf, int kt) {
    unsigned short* base = sm2 + buf * 20480;
    GLOAD_LDS16(aptr + kt * 32, base + tid * 8);
#pragma unroll
    for (int j = 0; j < 4; ++j)
      GLOAD_LDS16(bptr[j] + kt * 32, base + 4096 + (j * 512 + tid) * 8);
  };

  constexpr int NKT = NH / 32;  // 32
  stage(0, 0);
  stage(1, 1);
  for (int kt = 0; kt < NKT; ++kt) {
    if (kt + 1 < NKT)
      VMCNT(5);
    else
      VMCNT(0);
    __builtin_amdgcn_s_barrier();
    if (kt + 2 < NKT) stage((kt + 2) % 3, kt + 2);
    const unsigned short* base = sm2 + (kt % 3) * 20480;
    bf16x8 af[4], bf[8];
#pragma unroll
    for (int m = 0; m < 4; ++m)
      af[m] = __builtin_bit_cast(bf16x8, *(const ushort8v*)&base[aoff[m]]);
#pragma unroll
    for (int n = 0; n < 8; ++n)
      bf[n] = __builtin_bit_cast(bf16x8, *(const ushort8v*)&base[boff[n]]);
    __builtin_amdgcn_s_setprio(1);
#pragma unroll
    for (int m = 0; m < 4; ++m)
#pragma unroll
      for (int n = 0; n < 8; ++n)
        acc[m][n] = __builtin_amdgcn_mfma_f32_16x16x32_bf16(af[m], bf[n], acc[m][n], 0, 0, 0);
    __builtin_amdgcn_s_setprio(0);
  }
  __syncthreads();  // all reads done before C reuses LDS

  // Round acc + b2 to bf16 into C (bits == old FFv bits).
  unsigned short* C = sm2;  // [128][516]
  float bb[8];
#pragma unroll
  for (int n = 0; n < 8; ++n) bb[n] = b2[wn * 128 + n * 16 + fr];
#pragma unroll
  for (int m = 0; m < 4; ++m)
#pragma unroll
    for (int n = 0; n < 8; ++n) {
      const int col_l = wn * 128 + n * 16 + fr;
      const int row_l0 = wm * 64 + m * 16 + (fhi << 2);
#pragma unroll
      for (int i = 0; i < 4; ++i)
        C[(row_l0 + i) * 516 + col_l] = f2b(acc[m][n][i] + bb[n]);
    }
  __syncthreads();

  // Verbatim lnv body per row; wave w handles rows w, w+8, ..., w+120.
  for (int pass = 0; pass < 16; ++pass) {
    const int row_l = w + pass * 8;
    const int vrow = bm * 128 + row_l;
    ushort8v fv = *(const ushort8v*)&C[row_l * 516 + lane * 8];
    const float* er = emb + (size_t)vrow * ND + lane * 8;
    float4 e0 = *(const float4*)er, e1 = *(const float4*)(er + 4);
    float x[8] = {b2f(fv[0]) + e0.x, b2f(fv[1]) + e0.y, b2f(fv[2]) + e0.z, b2f(fv[3]) + e0.w,
                  b2f(fv[4]) + e1.x, b2f(fv[5]) + e1.y, b2f(fv[6]) + e1.z, b2f(fv[7]) + e1.w};
    float s = 0.f, sq = 0.f;
#pragma unroll
    for (int j = 0; j < 8; ++j) {
      s += x[j];
      sq += x[j] * x[j];
    }
#pragma unroll
    for (int o = 32; o; o >>= 1) {
      s += __shfl_xor(s, o);
      sq += __shfl_xor(sq, o);
    }
    const float mu = s * (1.f / 512.f);
    const float var = sq * (1.f / 512.f) - mu * mu;
    const float rs = rsqrtf(var + 1e-5f);
    float gd = 0.f;
    float h[8];
    ushort8v hv;
#pragma unroll
    for (int j = 0; j < 8; ++j) {
      const int col = lane * 8 + j;
      h[j] = (x[j] - mu) * rs * ln_g[col] + ln_b[col];
      hv[j] = f2b(h[j]);
      gd += h[j] * wg[col];
    }
    *(ushort8v*)&Hv[(size_t)vrow * ND + lane * 8] = hv;
#pragma unroll
    for (int o = 32; o; o >>= 1) gd += __shfl_xor(gd, o);
    if (lane == 0) gatev[vrow] = 1.f / (1.f + expf(-(gd + bgp[0])));
    for (int b = 0; b < NB; ++b) {
      if (seq[b * NT + NT - 1] == vrow) {
        float* hl = hlast + b * ND + lane * 8;
#pragma unroll
        for (int j = 0; j < 8; ++j) hl[j] = h[j];
      }
    }
  }
}

// ---------------------------------------------------------------------------
// Merged: blocks 0..15 = per-batch top-256 radix select (register keys, 1
// barrier/bit, packed scan, bits 31-30 skipped); blocks 16..143 = qpart.
// ---------------------------------------------------------------------------
__global__ __launch_bounds__(256) void topk_qpart_kernel(
    const float* __restrict__ gatev, const int* __restrict__ seq,
    int* __restrict__ topidx, const float* __restrict__ hlast,
    const float* __restrict__ wq, const float* __restrict__ bq,
    float* __restrict__ qpart) {
  __shared__ int wsum[2][4];
  __shared__ unsigned int scanbuf[256];
  const int tid = threadIdx.x;
  if (blockIdx.x >= 16) {
    const int blk = blockIdx.x - 16;
    const int b = blk >> 3, s = blk & 7;
    const int d0 = s * 64;
    float a0 = 0.f, a1 = 0.f;
#pragma unroll 4
    for (int dd = 0; dd < 64; ++dd) {
      const float hv = hlast[b * ND + d0 + dd];
      a0 += hv * wq[(size_t)(d0 + dd) * ND + tid];
      a1 += hv * wq[(size_t)(d0 + dd) * ND + tid + 256];
    }
    if (s == 0) {
      a0 += bq[tid];
      a1 += bq[tid + 256];
    }
    float* qp = qpart + ((size_t)b * 8 + s) * ND;
    qp[tid] = a0;
    qp[tid + 256] = a1;
    return;
  }
  const int b = blockIdx.x;
  const int wv = tid >> 6;
  const int lane = tid & 63;
  const int* sq_ = seq + (size_t)b * NT;
  const int base = tid * 16;
  unsigned int kreg[16];
#pragma unroll
  for (int j = 0; j < 16; ++j)
    kreg[j] = __builtin_bit_cast(unsigned int, gatev[sq_[base + j]]);

  unsigned int K = 0u;
  for (int bit = 29; bit >= 0; --bit) {
    const unsigned int cand = K | (1u << bit);
    int c = 0;
#pragma unroll
    for (int j = 0; j < 16; ++j) c += (kreg[j] >= cand) ? 1 : 0;
#pragma unroll
    for (int o = 32; o; o >>= 1) c += __shfl_xor(c, o);
    const int par = bit & 1;
    if (lane == 0) wsum[par][wv] = c;
    __syncthreads();
    const int tot = wsum[par][0] + wsum[par][1] + wsum[par][2] + wsum[par][3];
    if (tot >= NSLOTS) K = cand;
  }
  int gcnt = 0, ecnt = 0;
#pragma unroll
  for (int j = 0; j < 16; ++j) {
    gcnt += (kreg[j] > K) ? 1 : 0;
    ecnt += (kreg[j] == K) ? 1 : 0;
  }
  __syncthreads();
  scanbuf[tid] = ((unsigned int)gcnt << 16) | (unsigned int)ecnt;
  __syncthreads();
  for (int off = 1; off < 256; off <<= 1) {
    unsigned int v2 = (tid >= off) ? scanbuf[tid - off] : 0u;
    __syncthreads();
    scanbuf[tid] += v2;
    __syncthreads();
  }
  const unsigned int my = scanbuf[tid];
  const unsigned int tot = scanbuf[255];
  const int gi = (int)(my >> 16);
  const int ei = (int)(my & 0xFFFFu);
  const int tot_gt = (int)(tot >> 16);
  int gpos = gi - gcnt;
  int epos = tot_gt + (ei - ecnt);
  int* outp = topidx + b * NSLOTS;
#pragma unroll
  for (int j = 0; j < 16; ++j) {
    if (kreg[j] > K) {
      outp[gpos++] = base + j;
    } else if (kreg[j] == K) {
      if (epos < NSLOTS) outp[epos] = base + j;
      epos++;
    }
  }
}

// ---------------------------------------------------------------------------
// Fused scores + softmax + ctx. 64 blocks = 16 batches x 4 d-chunks of 128.
// ---------------------------------------------------------------------------
__global__ __launch_bounds__(256) void attn_kernel(
    const unsigned short* __restrict__ Hv, const int* __restrict__ seq,
    const float* __restrict__ qpart, const int* __restrict__ topidx,
    float* __restrict__ ctx) {
  __shared__ float qs[512];
  __shared__ float attnv[256];
  __shared__ int idxs[256];
  __shared__ float red[4];
  __shared__ float part[2][128];
  const int blk = blockIdx.x;
  const int b = blk >> 2, dc = blk & 3;
  const int tid = threadIdx.x;
  const int lane = tid & 63, wv = tid >> 6;
  {
    float a0 = 0.f, a1 = 0.f;
#pragma unroll
    for (int s = 0; s < 8; ++s) {
      const float* qp = qpart + ((size_t)b * 8 + s) * ND;
      a0 += qp[tid];
      a1 += qp[tid + 256];
    }
    qs[tid] = a0;
    qs[tid + 256] = a1;
  }
  idxs[tid] = seq[(size_t)b * NT + topidx[b * 256 + tid]];
  __syncthreads();
  const unsigned short* hr = Hv + (size_t)idxs[tid] * ND;
  float sc = 0.f;
  for (int d0 = 0; d0 < 512; d0 += 8) {
    ushort8v hv = *(const ushort8v*)&hr[d0];
#pragma unroll
    for (int j = 0; j < 8; ++j) sc += b2f(hv[j]) * qs[d0 + j];
  }
  float m = sc;
#pragma unroll
  for (int o = 32; o; o >>= 1) m = fmaxf(m, __shfl_xor(m, o));
  if (lane == 0) red[wv] = m;
  __syncthreads();
  m = fmaxf(fmaxf(red[0], red[1]), fmaxf(red[2], red[3]));
  __syncthreads();
  const float e = expf(sc - m);
  float ssum = e;
#pragma unroll
  for (int o = 32; o; o >>= 1) ssum += __shfl_xor(ssum, o);
  if (lane == 0) red[wv] = ssum;
  __syncthreads();
  ssum = red[0] + red[1] + red[2] + red[3];
  attnv[tid] = e / ssum;
  __syncthreads();
  const int d = dc * 128 + (tid & 127);
  const int kh = tid >> 7;
  float c = 0.f;
#pragma unroll 4
  for (int k2 = 0; k2 < 128; ++k2) {
    const int k = kh * 128 + k2;
    c += attnv[k] * b2f(Hv[(size_t)idxs[k] * ND + d]);
  }
  part[kh][tid & 127] = c;
  __syncthreads();
  if (tid < 128) ctx[b * 512 + dc * 128 + tid] = part[0][tid] + part[1][tid];
}

// ---------------------------------------------------------------------------
// Fused out-projection: 1000 blocks x 32 vocab cols; ctx in LDS; 8 D-groups.
// ---------------------------------------------------------------------------
__global__ __launch_bounds__(256) void out_fused_kernel(const float* __restrict__ ctx,
                                                        const float* __restrict__ wo,
                                                        const float* __restrict__ bo,
                                                        float* __restrict__ out) {
  __shared__ float cs[16 * 512];
  __shared__ float red[8][16][32];
  const int tid = threadIdx.x;
  const int c = tid & 31, g = tid >> 5;
  const int v0 = blockIdx.x * 32;
  for (int i = tid; i < 16 * 512; i += 256) cs[i] = ctx[i];
  __syncthreads();
  const int d0 = g * 64;
  float acc[16] = {};
  const float* wp = wo + (size_t)d0 * NV + v0 + c;
#pragma unroll 4
  for (int dd = 0; dd < 64; ++dd) {
    const float wv = wp[(size_t)dd * NV];
#pragma unroll
    for (int bb = 0; bb < 16; ++bb) acc[bb] += cs[bb * 512 + d0 + dd] * wv;
  }
#pragma unroll
  for (int bb = 0; bb < 16; ++bb) red[g][bb][c] = acc[bb];
  __syncthreads();
  for (int i = tid; i < 512; i += 256) {
    const int bb = i >> 5, cc = i & 31;
    float a = bo[v0 + cc];
#pragma unroll
    for (int gg = 0; gg < 8; ++gg) a += red[gg][bb][cc];
    out[(size_t)bb * NV + v0 + cc] = a;
  }
}

// ---------------------------------------------------------------------------
// Workspace layout (vocab-space; total ~181 MiB):
//   A1v   @ 0        : 32000x1024 bf16 = 62.5 MiB
//   embb  @ 96 MiB   : 31.25 MiB
//   Hv    @ 128 MiB  : 31.25 MiB
//   w1t   @ 177 MiB, w2t @ 178 MiB, smalls @ 180 MiB
// ---------------------------------------------------------------------------
extern "C" void kernel_launch(void* const* d_in, const int* in_sizes, int n_in,
                              void* d_out, int out_size, void* d_ws, size_t ws_size,
                              hipStream_t stream) {
  const int* seq = (const int*)d_in[0];
  const float* emb = (const float*)d_in[1];
  const float* w1 = (const float*)d_in[2];
  const float* b1 = (const float*)d_in[3];
  const float* w2 = (const float*)d_in[4];
  const float* b2 = (const float*)d_in[5];
  const float* ln_g = (const float*)d_in[6];
  const float* ln_b = (const float*)d_in[7];
  const float* wg = (const float*)d_in[8];
  const float* bg = (const float*)d_in[9];
  const float* wq = (const float*)d_in[10];
  const float* bq = (const float*)d_in[11];
  const float* wo = (const float*)d_in[12];
  const float* bo = (const float*)d_in[13];
  float* out = (float*)d_out;

  char* ws = (char*)d_ws;
  unsigned short* A1v = (unsigned short*)ws;                        // 62.5 MiB
  unsigned short* embb = (unsigned short*)(ws + ((size_t)96 << 20));
  unsigned short* Hv = (unsigned short*)(ws + ((size_t)128 << 20));
  unsigned short* w1t = (unsigned short*)(ws + ((size_t)177 << 20));
  unsigned short* w2t = (unsigned short*)(ws + ((size_t)178 << 20));
  char* sb = ws + ((size_t)180 << 20);
  float* gatev = (float*)sb;                                        // 128 KiB
  int* topidx = (int*)(sb + 131072);                                // 16 KiB
  float* hlast = (float*)(sb + 131072 + 16384);                     // 32 KiB
  float* ctxbuf = (float*)(sb + 131072 + 16384 + 32768);            // 32 KiB
  float* qpart = (float*)(sb + 131072 + 16384 + 65536);             // 256 KiB

  hipFuncSetAttribute(reinterpret_cast<const void*>(gemm2ln_kernel),
                      hipFuncAttributeMaxDynamicSharedMemorySize, 133120);

  cvtwt_kernel<<<12096, 256, 0, stream>>>(emb, embb, w1, w2, w1t, w2t);
  gemm128_kernel<512, 1024, 8, true>
      <<<2000, 256, 0, stream>>>(embb, w1t, b1, A1v);
  gemm2ln_kernel<<<250, 512, 133120, stream>>>(A1v, w2t, b2, emb, ln_g, ln_b, wg, bg,
                                               Hv, gatev, seq, hlast);
  topk_qpart_kernel<<<144, 256, 0, stream>>>(gatev, seq, topidx, hlast, wq, bq, qpart);
  attn_kernel<<<64, 256, 0, stream>>>(Hv, seq, qpart, topidx, ctxbuf);
  out_fused_kernel<<<1000, 256, 0, stream>>>(ctxbuf, wo, bo, out);
}

// Round 16
// 182.033 us; speedup vs baseline: 1.1336x; 1.0102x over previous
//
#include <hip/hip_runtime.h>

typedef __bf16 bf16x8 __attribute__((ext_vector_type(8)));
typedef float f32x4 __attribute__((ext_vector_type(4)));
typedef unsigned short ushort8v __attribute__((ext_vector_type(8)));

#define NB 16
#define NT 4096
#define NV 32000
#define ND 512
#define NH 1024
#define NSLOTS 256

__device__ __forceinline__ float b2f(unsigned short u) {
  unsigned int x = ((unsigned int)u) << 16;
  return __builtin_bit_cast(float, x);
}
__device__ __forceinline__ unsigned short f2b(float f) {
  unsigned int x = __builtin_bit_cast(unsigned int, f);
  unsigned int r = (x + 0x7FFFu + ((x >> 16) & 1u)) >> 16;
  return (unsigned short)r;
}

#define GLOAD_LDS16(g, l)                                                              \
  __builtin_amdgcn_global_load_lds((const __attribute__((address_space(1))) void*)(g), \
                                   (__attribute__((address_space(3))) void*)(l), 16, 0, 0)
#define BARRIER() asm volatile("s_barrier" ::: "memory")
#define VMCNT(n) asm volatile("s_waitcnt vmcnt(" #n ")" ::: "memory")

// ---------------------------------------------------------------------------
// Fused elementwise prep: emb f32->bf16 (blocks <8000) and w1/w2 transpose+cvt.
// ---------------------------------------------------------------------------
__global__ __launch_bounds__(256) void cvtwt_kernel(
    const float* __restrict__ emb, unsigned short* __restrict__ embb,
    const float* __restrict__ w1, const float* __restrict__ w2,
    unsigned short* __restrict__ w1t, unsigned short* __restrict__ w2t) {
  const int blk = blockIdx.x;
  if (blk < 8000) {
    const long base = ((long)blk * 256 + threadIdx.x) * 8;
    float4 a = *(const float4*)&emb[base];
    float4 b = *(const float4*)&emb[base + 4];
    ushort8v o;
    o[0] = f2b(a.x); o[1] = f2b(a.y); o[2] = f2b(a.z); o[3] = f2b(a.w);
    o[4] = f2b(b.x); o[5] = f2b(b.y); o[6] = f2b(b.z); o[7] = f2b(b.w);
    *(ushort8v*)&embb[base] = o;
  } else {
    const int i = (blk - 8000) * 256 + threadIdx.x;
    if (i < ND * NH) {
      const int n = i >> 9, k = i & 511;
      w1t[i] = f2b(w1[k * NH + n]);
    } else {
      const int j = i - ND * NH;
      const int n = j >> 10, k = j & 1023;
      w2t[j] = f2b(w2[k * ND + n]);
    }
  }
}

// ---------------------------------------------------------------------------
// gemm1: 128x256 bf16 MFMA tiles over vocab rows (M=32000, N=1024, K=512).
// r6 skeleton with fatter N-tile: BK=32, 3-deep counted-vmcnt pipeline
// (6 loads/thread/stage -> vmcnt(6)), (row>>1)&3 XOR chunk swizzle
// (both-sides, r6-verified), XCD swizzle (1000 blocks % 8 == 0), setprio.
// 4 waves (2M x 2N), per-wave 64x128 out (32 MFMA per barrier window),
// 72 KiB dynamic LDS -> 2 blocks/CU. Per-element K-order identical to the
// 128x128 version (same kt sequence) -> bit-exact outputs.
// ---------------------------------------------------------------------------
template <int KDIM, int NLD, int NBN, bool RELU>
__global__ __launch_bounds__(256, 2) void gemm1_kernel(
    const unsigned short* __restrict__ Abase, const unsigned short* __restrict__ Bt,
    const float* __restrict__ bias, unsigned short* __restrict__ Out) {
  extern __shared__ unsigned short sm1[];  // 3 bufs x (A 4096 | B 8192) shorts | C [128][264]
  const int tid = threadIdx.x;
  const int lane = tid & 63;
  const int w = tid >> 6;
  const int wm = w >> 1, wn = w & 1;

  const int id = blockIdx.x;
  const int swz = (id & 7) * (gridDim.x >> 3) + (id >> 3);
  const int bm = swz / NBN;
  const int bn = swz % NBN;

  // Staging: A tile 128x32 (512 chunks, 2/thread), B tile 256x32 (1024, 4/thread).
  // LDS slot (row,c) holds global chunk c ^ ((row>>1)&3).
  const unsigned short* aptr[2];
#pragma unroll
  for (int j = 0; j < 2; ++j) {
    const int c = j * 256 + tid;
    const int row = c >> 2;
    const int sc = (c & 3) ^ ((row >> 1) & 3);
    aptr[j] = Abase + (size_t)(bm * 128 + row) * KDIM + sc * 8;
  }
  const unsigned short* bptr[4];
#pragma unroll
  for (int j = 0; j < 4; ++j) {
    const int c = j * 256 + tid;
    const int row = c >> 2;
    const int sc = (c & 3) ^ ((row >> 1) & 3);
    bptr[j] = Bt + (size_t)(bn * 256 + row) * KDIM + sc * 8;
  }

  const int fr = lane & 15;
  const int fhi = lane >> 4;
  const int fsw = (fr >> 1) & 3;
  const int fchunk = (fhi ^ fsw) * 8;
  int aoff[4], boff[8];
#pragma unroll
  for (int m = 0; m < 4; ++m) aoff[m] = (wm * 64 + m * 16 + fr) * 32 + fchunk;
#pragma unroll
  for (int n = 0; n < 8; ++n) boff[n] = 4096 + (wn * 128 + n * 16 + fr) * 32 + fchunk;

  f32x4 acc[4][8] = {};

  auto stage = [&](int buf, int kt) {
    unsigned short* base = sm1 + buf * 12288;
#pragma unroll
    for (int j = 0; j < 2; ++j)
      GLOAD_LDS16(aptr[j] + kt * 32, base + (j * 256 + w * 64) * 8);
#pragma unroll
    for (int j = 0; j < 4; ++j)
      GLOAD_LDS16(bptr[j] + kt * 32, base + 4096 + (j * 256 + w * 64) * 8);
  };

  constexpr int NKT = KDIM / 32;  // 16
  stage(0, 0);
  stage(1, 1);
  for (int kt = 0; kt < NKT; ++kt) {
    if (kt + 1 < NKT)
      VMCNT(6);
    else
      VMCNT(0);
    __builtin_amdgcn_s_barrier();
    if (kt + 2 < NKT) stage((kt + 2) % 3, kt + 2);
    const unsigned short* base = sm1 + (kt % 3) * 12288;
    bf16x8 af[4], bf[8];
#pragma unroll
    for (int m = 0; m < 4; ++m)
      af[m] = __builtin_bit_cast(bf16x8, *(const ushort8v*)&base[aoff[m]]);
#pragma unroll
    for (int n = 0; n < 8; ++n)
      bf[n] = __builtin_bit_cast(bf16x8, *(const ushort8v*)&base[boff[n]]);
    __builtin_amdgcn_s_setprio(1);
#pragma unroll
    for (int m = 0; m < 4; ++m)
#pragma unroll
      for (int n = 0; n < 8; ++n)
        acc[m][n] = __builtin_amdgcn_mfma_f32_16x16x32_bf16(af[m], bf[n], acc[m][n], 0, 0, 0);
    __builtin_amdgcn_s_setprio(0);
  }
  __builtin_amdgcn_s_barrier();  // all reads done before C reuses LDS

  // Epilogue: bias (+relu); repack through padded LDS [128][264].
  unsigned short* C = sm1;
  float bb[8];
#pragma unroll
  for (int n = 0; n < 8; ++n) bb[n] = bias[bn * 256 + wn * 128 + n * 16 + fr];
#pragma unroll
  for (int m = 0; m < 4; ++m)
#pragma unroll
    for (int n = 0; n < 8; ++n) {
      const int col_l = wn * 128 + n * 16 + fr;
      const int row_l0 = wm * 64 + m * 16 + (fhi << 2);
#pragma unroll
      for (int i = 0; i < 4; ++i) {
        float v = acc[m][n][i] + bb[n];
        if constexpr (RELU) v = fmaxf(v, 0.f);
        C[(row_l0 + i) * 264 + col_l] = f2b(v);
      }
    }
  __syncthreads();
#pragma unroll
  for (int it = 0; it < 16; ++it) {
    const int idx = it * 256 + tid;
    const int row = idx >> 5;
    const int pos = idx & 31;
    ushort8v v = *(const ushort8v*)&C[row * 264 + pos * 8];
    *(ushort8v*)&Out[(size_t)(bm * 128 + row) * (size_t)NLD + bn * 256 + pos * 8] = v;
  }
}

// ---------------------------------------------------------------------------
// Fused gemm2 + residual + LayerNorm + gate. 250 blocks x 512 threads.
// Tile 128x512, 8 waves (2M x 4N), BK=32, 3-deep counted-vmcnt (vmcnt(5)),
// (row>>1)&3 XOR swizzle. Epilogue: acc+b2 -> bf16 LDS C (bits == old FFv),
// then verbatim lnv body per row -> Hv, gatev, hlast.
// ---------------------------------------------------------------------------
__global__ __launch_bounds__(512, 2) void gemm2ln_kernel(
    const unsigned short* __restrict__ A1v, const unsigned short* __restrict__ w2t,
    const float* __restrict__ b2, const float* __restrict__ emb,
    const float* __restrict__ ln_g, const float* __restrict__ ln_b,
    const float* __restrict__ wg, const float* __restrict__ bgp,
    unsigned short* __restrict__ Hv, float* __restrict__ gatev,
    const int* __restrict__ seq, float* __restrict__ hlast) {
  extern __shared__ unsigned short sm2[];  // 3 bufs x 20480 shorts | C [128][516]
  const int tid = threadIdx.x;
  const int lane = tid & 63;
  const int w = tid >> 6;
  const int wm = w >> 2;
  const int wn = w & 3;

  const int id = blockIdx.x, nwg = gridDim.x;
  const int q = nwg >> 3, r = nwg & 7;
  const int xcd = id & 7;
  const int bm = ((xcd < r) ? xcd * (q + 1) : r * (q + 1) + (xcd - r) * q) + (id >> 3);

  const int arow = tid >> 2;
  const int acol = (tid & 3) ^ ((arow >> 1) & 3);
  const unsigned short* aptr = A1v + (size_t)(bm * 128 + arow) * NH + acol * 8;
  const unsigned short* bptr[4];
#pragma unroll
  for (int j = 0; j < 4; ++j) {
    const int c = j * 512 + tid;
    const int brow = c >> 2;
    const int bcol = (c & 3) ^ ((brow >> 1) & 3);
    bptr[j] = w2t + (size_t)brow * NH + bcol * 8;
  }

  const int fr = lane & 15;
  const int fhi = lane >> 4;
  const int fsw = (fr >> 1) & 3;
  const int fchunk = (fhi ^ fsw) * 8;
  int aoff[4], boff[8];
#pragma unroll
  for (int m = 0; m < 4; ++m) aoff[m] = (wm * 64 + m * 16 + fr) * 32 + fchunk;
#pragma unroll
  for (int n = 0; n < 8; ++n) boff[n] = 4096 + (wn * 128 + n * 16 + fr) * 32 + fchunk;

  f32x4 acc[4][8] = {};

  auto stage = [&](int buf, int kt) {
    unsigned short* base = sm2 + buf * 20480;
    GLOAD_LDS16(aptr + kt * 32, base + tid * 8);
#pragma unroll
    for (int j = 0; j < 4; ++j)
      GLOAD_LDS16(bptr[j] + kt * 32, base + 4096 + (j * 512 + tid) * 8);
  };

  constexpr int NKT = NH / 32;  // 32
  stage(0, 0);
  stage(1, 1);
  for (int kt = 0; kt < NKT; ++kt) {
    if (kt + 1 < NKT)
      VMCNT(5);
    else
      VMCNT(0);
    __builtin_amdgcn_s_barrier();
    if (kt + 2 < NKT) stage((kt + 2) % 3, kt + 2);
    const unsigned short* base = sm2 + (kt % 3) * 20480;
    bf16x8 af[4], bf[8];
#pragma unroll
    for (int m = 0; m < 4; ++m)
      af[m] = __builtin_bit_cast(bf16x8, *(const ushort8v*)&base[aoff[m]]);
#pragma unroll
    for (int n = 0; n < 8; ++n)
      bf[n] = __builtin_bit_cast(bf16x8, *(const ushort8v*)&base[boff[n]]);
    __builtin_amdgcn_s_setprio(1);
#pragma unroll
    for (int m = 0; m < 4; ++m)
#pragma unroll
      for (int n = 0; n < 8; ++n)
        acc[m][n] = __builtin_amdgcn_mfma_f32_16x16x32_bf16(af[m], bf[n], acc[m][n], 0, 0, 0);
    __builtin_amdgcn_s_setprio(0);
  }
  __syncthreads();

  unsigned short* C = sm2;  // [128][516]
  float bb[8];
#pragma unroll
  for (int n = 0; n < 8; ++n) bb[n] = b2[wn * 128 + n * 16 + fr];
#pragma unroll
  for (int m = 0; m < 4; ++m)
#pragma unroll
    for (int n = 0; n < 8; ++n) {
      const int col_l = wn * 128 + n * 16 + fr;
      const int row_l0 = wm * 64 + m * 16 + (fhi << 2);
#pragma unroll
      for (int i = 0; i < 4; ++i)
        C[(row_l0 + i) * 516 + col_l] = f2b(acc[m][n][i] + bb[n]);
    }
  __syncthreads();

  for (int pass = 0; pass < 16; ++pass) {
    const int row_l = w + pass * 8;
    const int vrow = bm * 128 + row_l;
    ushort8v fv = *(const ushort8v*)&C[row_l * 516 + lane * 8];
    const float* er = emb + (size_t)vrow * ND + lane * 8;
    float4 e0 = *(const float4*)er, e1 = *(const float4*)(er + 4);
    float x[8] = {b2f(fv[0]) + e0.x, b2f(fv[1]) + e0.y, b2f(fv[2]) + e0.z, b2f(fv[3]) + e0.w,
                  b2f(fv[4]) + e1.x, b2f(fv[5]) + e1.y, b2f(fv[6]) + e1.z, b2f(fv[7]) + e1.w};
    float s = 0.f, sq = 0.f;
#pragma unroll
    for (int j = 0; j < 8; ++j) {
      s += x[j];
      sq += x[j] * x[j];
    }
#pragma unroll
    for (int o = 32; o; o >>= 1) {
      s += __shfl_xor(s, o);
      sq += __shfl_xor(sq, o);
    }
    const float mu = s * (1.f / 512.f);
    const float var = sq * (1.f / 512.f) - mu * mu;
    const float rs = rsqrtf(var + 1e-5f);
    float gd = 0.f;
    float h[8];
    ushort8v hv;
#pragma unroll
    for (int j = 0; j < 8; ++j) {
      const int col = lane * 8 + j;
      h[j] = (x[j] - mu) * rs * ln_g[col] + ln_b[col];
      hv[j] = f2b(h[j]);
      gd += h[j] * wg[col];
    }
    *(ushort8v*)&Hv[(size_t)vrow * ND + lane * 8] = hv;
#pragma unroll
    for (int o = 32; o; o >>= 1) gd += __shfl_xor(gd, o);
    if (lane == 0) gatev[vrow] = 1.f / (1.f + expf(-(gd + bgp[0])));
    for (int b = 0; b < NB; ++b) {
      if (seq[b * NT + NT - 1] == vrow) {
        float* hl = hlast + b * ND + lane * 8;
#pragma unroll
        for (int j = 0; j < 8; ++j) hl[j] = h[j];
      }
    }
  }
}

// ---------------------------------------------------------------------------
// Merged: blocks 0..15 = per-batch top-256 radix select; blocks 16..143 = qpart.
// ---------------------------------------------------------------------------
__global__ __launch_bounds__(256) void topk_qpart_kernel(
    const float* __restrict__ gatev, const int* __restrict__ seq,
    int* __restrict__ topidx, const float* __restrict__ hlast,
    const float* __restrict__ wq, const float* __restrict__ bq,
    float* __restrict__ qpart) {
  __shared__ int wsum[2][4];
  __shared__ unsigned int scanbuf[256];
  const int tid = threadIdx.x;
  if (blockIdx.x >= 16) {
    const int blk = blockIdx.x - 16;
    const int b = blk >> 3, s = blk & 7;
    const int d0 = s * 64;
    float a0 = 0.f, a1 = 0.f;
#pragma unroll 4
    for (int dd = 0; dd < 64; ++dd) {
      const float hv = hlast[b * ND + d0 + dd];
      a0 += hv * wq[(size_t)(d0 + dd) * ND + tid];
      a1 += hv * wq[(size_t)(d0 + dd) * ND + tid + 256];
    }
    if (s == 0) {
      a0 += bq[tid];
      a1 += bq[tid + 256];
    }
    float* qp = qpart + ((size_t)b * 8 + s) * ND;
    qp[tid] = a0;
    qp[tid + 256] = a1;
    return;
  }
  const int b = blockIdx.x;
  const int wv = tid >> 6;
  const int lane = tid & 63;
  const int* sq_ = seq + (size_t)b * NT;
  const int base = tid * 16;
  unsigned int kreg[16];
#pragma unroll
  for (int j = 0; j < 16; ++j)
    kreg[j] = __builtin_bit_cast(unsigned int, gatev[sq_[base + j]]);

  unsigned int K = 0u;
  for (int bit = 29; bit >= 0; --bit) {
    const unsigned int cand = K | (1u << bit);
    int c = 0;
#pragma unroll
    for (int j = 0; j < 16; ++j) c += (kreg[j] >= cand) ? 1 : 0;
#pragma unroll
    for (int o = 32; o; o >>= 1) c += __shfl_xor(c, o);
    const int par = bit & 1;
    if (lane == 0) wsum[par][wv] = c;
    __syncthreads();
    const int tot = wsum[par][0] + wsum[par][1] + wsum[par][2] + wsum[par][3];
    if (tot >= NSLOTS) K = cand;
  }
  int gcnt = 0, ecnt = 0;
#pragma unroll
  for (int j = 0; j < 16; ++j) {
    gcnt += (kreg[j] > K) ? 1 : 0;
    ecnt += (kreg[j] == K) ? 1 : 0;
  }
  __syncthreads();
  scanbuf[tid] = ((unsigned int)gcnt << 16) | (unsigned int)ecnt;
  __syncthreads();
  for (int off = 1; off < 256; off <<= 1) {
    unsigned int v2 = (tid >= off) ? scanbuf[tid - off] : 0u;
    __syncthreads();
    scanbuf[tid] += v2;
    __syncthreads();
  }
  const unsigned int my = scanbuf[tid];
  const unsigned int tot = scanbuf[255];
  const int gi = (int)(my >> 16);
  const int ei = (int)(my & 0xFFFFu);
  const int tot_gt = (int)(tot >> 16);
  int gpos = gi - gcnt;
  int epos = tot_gt + (ei - ecnt);
  int* outp = topidx + b * NSLOTS;
#pragma unroll
  for (int j = 0; j < 16; ++j) {
    if (kreg[j] > K) {
      outp[gpos++] = base + j;
    } else if (kreg[j] == K) {
      if (epos < NSLOTS) outp[epos] = base + j;
      epos++;
    }
  }
}

// ---------------------------------------------------------------------------
// Fused scores + softmax + ctx. 64 blocks = 16 batches x 4 d-chunks of 128.
// ---------------------------------------------------------------------------
__global__ __launch_bounds__(256) void attn_kernel(
    const unsigned short* __restrict__ Hv, const int* __restrict__ seq,
    const float* __restrict__ qpart, const int* __restrict__ topidx,
    float* __restrict__ ctx) {
  __shared__ float qs[512];
  __shared__ float attnv[256];
  __shared__ int idxs[256];
  __shared__ float red[4];
  __shared__ float part[2][128];
  const int blk = blockIdx.x;
  const int b = blk >> 2, dc = blk & 3;
  const int tid = threadIdx.x;
  const int lane = tid & 63, wv = tid >> 6;
  {
    float a0 = 0.f, a1 = 0.f;
#pragma unroll
    for (int s = 0; s < 8; ++s) {
      const float* qp = qpart + ((size_t)b * 8 + s) * ND;
      a0 += qp[tid];
      a1 += qp[tid + 256];
    }
    qs[tid] = a0;
    qs[tid + 256] = a1;
  }
  idxs[tid] = seq[(size_t)b * NT + topidx[b * 256 + tid]];
  __syncthreads();
  const unsigned short* hr = Hv + (size_t)idxs[tid] * ND;
  float sc = 0.f;
  for (int d0 = 0; d0 < 512; d0 += 8) {
    ushort8v hv = *(const ushort8v*)&hr[d0];
#pragma unroll
    for (int j = 0; j < 8; ++j) sc += b2f(hv[j]) * qs[d0 + j];
  }
  float m = sc;
#pragma unroll
  for (int o = 32; o; o >>= 1) m = fmaxf(m, __shfl_xor(m, o));
  if (lane == 0) red[wv] = m;
  __syncthreads();
  m = fmaxf(fmaxf(red[0], red[1]), fmaxf(red[2], red[3]));
  __syncthreads();
  const float e = expf(sc - m);
  float ssum = e;
#pragma unroll
  for (int o = 32; o; o >>= 1) ssum += __shfl_xor(ssum, o);
  if (lane == 0) red[wv] = ssum;
  __syncthreads();
  ssum = red[0] + red[1] + red[2] + red[3];
  attnv[tid] = e / ssum;
  __syncthreads();
  const int d = dc * 128 + (tid & 127);
  const int kh = tid >> 7;
  float c = 0.f;
#pragma unroll 4
  for (int k2 = 0; k2 < 128; ++k2) {
    const int k = kh * 128 + k2;
    c += attnv[k] * b2f(Hv[(size_t)idxs[k] * ND + d]);
  }
  part[kh][tid & 127] = c;
  __syncthreads();
  if (tid < 128) ctx[b * 512 + dc * 128 + tid] = part[0][tid] + part[1][tid];
}

// ---------------------------------------------------------------------------
// Fused out-projection: 1000 blocks x 32 vocab cols; ctx in LDS; 8 D-groups.
// ---------------------------------------------------------------------------
__global__ __launch_bounds__(256) void out_fused_kernel(const float* __restrict__ ctx,
                                                        const float* __restrict__ wo,
                                                        const float* __restrict__ bo,
                                                        float* __restrict__ out) {
  __shared__ float cs[16 * 512];
  __shared__ float red[8][16][32];
  const int tid = threadIdx.x;
  const int c = tid & 31, g = tid >> 5;
  const int v0 = blockIdx.x * 32;
  for (int i = tid; i < 16 * 512; i += 256) cs[i] = ctx[i];
  __syncthreads();
  const int d0 = g * 64;
  float acc[16] = {};
  const float* wp = wo + (size_t)d0 * NV + v0 + c;
#pragma unroll 4
  for (int dd = 0; dd < 64; ++dd) {
    const float wv = wp[(size_t)dd * NV];
#pragma unroll
    for (int bb = 0; bb < 16; ++bb) acc[bb] += cs[bb * 512 + d0 + dd] * wv;
  }
#pragma unroll
  for (int bb = 0; bb < 16; ++bb) red[g][bb][c] = acc[bb];
  __syncthreads();
  for (int i = tid; i < 512; i += 256) {
    const int bb = i >> 5, cc = i & 31;
    float a = bo[v0 + cc];
#pragma unroll
    for (int gg = 0; gg < 8; ++gg) a += red[gg][bb][cc];
    out[(size_t)bb * NV + v0 + cc] = a;
  }
}

// ---------------------------------------------------------------------------
// Workspace layout (vocab-space; total ~181 MiB):
//   A1v @ 0, embb @ 96 MiB, Hv @ 128 MiB, w1t @ 177 MiB, w2t @ 178 MiB,
//   smalls @ 180 MiB.
// ---------------------------------------------------------------------------
extern "C" void kernel_launch(void* const* d_in, const int* in_sizes, int n_in,
                              void* d_out, int out_size, void* d_ws, size_t ws_size,
                              hipStream_t stream) {
  const int* seq = (const int*)d_in[0];
  const float* emb = (const float*)d_in[1];
  const float* w1 = (const float*)d_in[2];
  const float* b1 = (const float*)d_in[3];
  const float* w2 = (const float*)d_in[4];
  const float* b2 = (const float*)d_in[5];
  const float* ln_g = (const float*)d_in[6];
  const float* ln_b = (const float*)d_in[7];
  const float* wg = (const float*)d_in[8];
  const float* bg = (const float*)d_in[9];
  const float* wq = (const float*)d_in[10];
  const float* bq = (const float*)d_in[11];
  const float* wo = (const float*)d_in[12];
  const float* bo = (const float*)d_in[13];
  float* out = (float*)d_out;

  char* ws = (char*)d_ws;
  unsigned short* A1v = (unsigned short*)ws;                        // 62.5 MiB
  unsigned short* embb = (unsigned short*)(ws + ((size_t)96 << 20));
  unsigned short* Hv = (unsigned short*)(ws + ((size_t)128 << 20));
  unsigned short* w1t = (unsigned short*)(ws + ((size_t)177 << 20));
  unsigned short* w2t = (unsigned short*)(ws + ((size_t)178 << 20));
  char* sb = ws + ((size_t)180 << 20);
  float* gatev = (float*)sb;                                        // 128 KiB
  int* topidx = (int*)(sb + 131072);                                // 16 KiB
  float* hlast = (float*)(sb + 131072 + 16384);                     // 32 KiB
  float* ctxbuf = (float*)(sb + 131072 + 16384 + 32768);            // 32 KiB
  float* qpart = (float*)(sb + 131072 + 16384 + 65536);             // 256 KiB

  hipFuncSetAttribute(reinterpret_cast<const void*>(gemm1_kernel<512, 1024, 4, true>),
                      hipFuncAttributeMaxDynamicSharedMemorySize, 73728);
  hipFuncSetAttribute(reinterpret_cast<const void*>(gemm2ln_kernel),
                      hipFuncAttributeMaxDynamicSharedMemorySize, 133120);

  cvtwt_kernel<<<12096, 256, 0, stream>>>(emb, embb, w1, w2, w1t, w2t);
  gemm1_kernel<512, 1024, 4, true>
      <<<1000, 256, 73728, stream>>>(embb, w1t, b1, A1v);
  gemm2ln_kernel<<<250, 512, 133120, stream>>>(A1v, w2t, b2, emb, ln_g, ln_b, wg, bg,
                                               Hv, gatev, seq, hlast);
  topk_qpart_kernel<<<144, 256, 0, stream>>>(gatev, seq, topidx, hlast, wq, bq, qpart);
  attn_kernel<<<64, 256, 0, stream>>>(Hv, seq, qpart, topidx, ctxbuf);
  out_fused_kernel<<<1000, 256, 0, stream>>>(ctxbuf, wo, bo, out);
}